// Round 1
// baseline (546.818 us; speedup 1.0000x reference)
//
#include <hip/hip_runtime.h>

#define LDIM 12288
#define BDIM 2
#define KDIM 32
#define IDIM 768
#define CTD 128
#define CAD 16

__device__ __forceinline__ int clampi(int v, int lo, int hi) {
    return v < lo ? lo : (v > hi ? hi : v);
}

// bool inputs may arrive as int32 (fmt 0), raw bytes (fmt 1), or float32 (fmt 2)
__device__ __forceinline__ bool load_mask(const unsigned char* __restrict__ p, int i, int fmt) {
    if (fmt == 0) return ((const int*)p)[i] != 0;
    if (fmt == 1) return p[i] != 0;
    return ((const float*)p)[i] != 0.0f;
}

// ---------------- S_l / S_m : relu(C_L) @ W_single_{l,m}  + bool-format probe ----------------
__global__ __launch_bounds__(256) void k_single(
        const float* __restrict__ C_L,
        const float* __restrict__ Wsl, const float* __restrict__ Wsm,
        const unsigned char* __restrict__ seq_bool,
        float* __restrict__ S_l, float* __restrict__ S_m, int* __restrict__ flag)
{
    if (blockIdx.x == 0 && threadIdx.x == 0) {
        // probe first 64 int32 slots of is_motif_seq
        const unsigned* pi = (const unsigned*)seq_bool;
        bool isf = false, isb = false;
        for (int i = 0; i < 64; ++i) {
            unsigned v = pi[i];
            if (v == 0x3f800000u) isf = true;
            else if (v > 1u) isb = true;
        }
        *flag = isf ? 2 : (isb ? 1 : 0);
    }
    __shared__ float lds[4][144];   // 4 waves x (4 groups * 36-float padded stride)
    const int lane = threadIdx.x & 63;
    const int wid  = threadIdx.x >> 6;
    const int c = lane & 15, g = lane >> 4;
    // hoist weights: lane covers t in [32g, 32g+32), column c
    float wl[32], wm[32];
#pragma unroll
    for (int i = 0; i < 32; ++i) {
        int t = g * 32 + i;
        wl[i] = Wsl[t * 16 + c];
        wm[i] = Wsm[t * 16 + c];
    }
    const int NR = BDIM * LDIM;
    const int NW = gridDim.x * 4;
    for (int row = blockIdx.x * 4 + wid; row < NR; row += NW) {
        float2 x = ((const float2*)(C_L + (size_t)row * CTD))[lane];
        x.x = fmaxf(x.x, 0.f); x.y = fmaxf(x.y, 0.f);
        ((float2*)(&lds[wid][g * 36]))[c] = x;          // element t=32g+2c
        float al = 0.f, am = 0.f;
#pragma unroll
        for (int i = 0; i < 8; ++i) {
            float4 v = ((const float4*)(&lds[wid][g * 36]))[i];
            al = fmaf(v.x, wl[4*i+0], al); am = fmaf(v.x, wm[4*i+0], am);
            al = fmaf(v.y, wl[4*i+1], al); am = fmaf(v.y, wm[4*i+1], am);
            al = fmaf(v.z, wl[4*i+2], al); am = fmaf(v.z, wm[4*i+2], am);
            al = fmaf(v.w, wl[4*i+3], al); am = fmaf(v.w, wm[4*i+3], am);
        }
        al += __shfl_xor(al, 16); am += __shfl_xor(am, 16);
        al += __shfl_xor(al, 32); am += __shfl_xor(am, 32);
        if (lane < 16)      S_l[(size_t)row * 16 + c] = al;
        else if (lane < 32) S_m[(size_t)row * 16 + c] = am;
    }
}

// ---------------- Z_proc = (RMSNorm(Z) * rms_w) @ W_z ----------------
__global__ __launch_bounds__(256) void k_zproc(
        const float* __restrict__ Z, const float* __restrict__ rms_w,
        const float* __restrict__ Wz, float* __restrict__ Zp)
{
    __shared__ float lds[4][144];
    const int lane = threadIdx.x & 63;
    const int wid  = threadIdx.x >> 6;
    const int c = lane & 15, g = lane >> 4;
    float wz[32];
#pragma unroll
    for (int i = 0; i < 32; ++i) wz[i] = Wz[(g * 32 + i) * 16 + c];
    const float rw0 = rms_w[2 * lane], rw1 = rms_w[2 * lane + 1];
    const int NR = IDIM * IDIM;
    const int NW = gridDim.x * 4;
    for (int row = blockIdx.x * 4 + wid; row < NR; row += NW) {
        float2 x = ((const float2*)(Z + (size_t)row * CTD))[lane];
        float ss = x.x * x.x + x.y * x.y;
#pragma unroll
        for (int d = 1; d < 64; d <<= 1) ss += __shfl_xor(ss, d);
        float scale = rsqrtf(ss * (1.0f / 128.0f) + 1e-6f);
        float2 xs; xs.x = x.x * rw0; xs.y = x.y * rw1;
        ((float2*)(&lds[wid][g * 36]))[c] = xs;
        float acc = 0.f;
#pragma unroll
        for (int i = 0; i < 8; ++i) {
            float4 v = ((const float4*)(&lds[wid][g * 36]))[i];
            acc = fmaf(v.x, wz[4*i+0], acc);
            acc = fmaf(v.y, wz[4*i+1], acc);
            acc = fmaf(v.z, wz[4*i+2], acc);
            acc = fmaf(v.w, wz[4*i+3], acc);
        }
        acc += __shfl_xor(acc, 16);
        acc += __shfl_xor(acc, 32);
        if (lane < 16) Zp[(size_t)row * 16 + c] = acc * scale;
    }
}

// ---------------- main pair kernel: one thread per (b,l,k) row ----------------
template <int ZMODE>   // 1: read precomputed Zp; 0: recompute RMSNorm+Wz inline
__global__ __launch_bounds__(256) void k_pair(
        const float* __restrict__ motif_pos, const unsigned char* __restrict__ is_motif_coord,
        const float* __restrict__ ref_pos, const int* __restrict__ ref_uid,
        const unsigned char* __restrict__ is_motif_seq, const int* __restrict__ indices,
        const int* __restrict__ tok_idx,
        const float* __restrict__ Wdm, const float* __restrict__ Winvm, const float* __restrict__ Wmaskm,
        const float* __restrict__ Wdr, const float* __restrict__ Winvr, const float* __restrict__ Wmaskr,
        const float* __restrict__ S_l, const float* __restrict__ S_m,
        const float* __restrict__ Zp,
        const float* __restrict__ Z, const float* __restrict__ rms_w, const float* __restrict__ Wz,
        const float* __restrict__ W1, const float* __restrict__ W2, const float* __restrict__ W3,
        const int* __restrict__ flag, float* __restrict__ out)
{
    const int row = blockIdx.x * blockDim.x + threadIdx.x;
    if (row >= BDIM * LDIM * KDIM) return;
    const int fmt = *flag;
    const int bl = row >> 5;            // b*L + l   (K=32)
    const int l  = bl % LDIM;
    int j = indices[row];
    j = clampi(j, 0, LDIM - 1);

    float p[16];
    // singles + token-pair features
    {
        const float4* sl = (const float4*)(S_l + (size_t)bl * 16);
        const float4* sm = (const float4*)(S_m + (size_t)(bl - l + j) * 16);
#pragma unroll
        for (int q = 0; q < 4; ++q) {
            float4 a = sl[q], b = sm[q];
            p[4*q+0] = a.x + b.x; p[4*q+1] = a.y + b.y;
            p[4*q+2] = a.z + b.z; p[4*q+3] = a.w + b.w;
        }
        const int tq = clampi(tok_idx[l], 0, IDIM - 1);
        const int tk = clampi(tok_idx[j], 0, IDIM - 1);
        if (ZMODE) {
            const float4* zp = (const float4*)(Zp + ((size_t)tq * IDIM + tk) * 16);
#pragma unroll
            for (int q = 0; q < 4; ++q) {
                float4 z = zp[q];
                p[4*q+0] += z.x; p[4*q+1] += z.y; p[4*q+2] += z.z; p[4*q+3] += z.w;
            }
        } else {
            const float4* z4 = (const float4*)(Z + ((size_t)tq * IDIM + tk) * CTD);
            float ss = 0.f, za[16];
#pragma unroll
            for (int c2 = 0; c2 < 16; ++c2) za[c2] = 0.f;
#pragma unroll
            for (int q = 0; q < 32; ++q) {
                float4 v = z4[q];
                ss += v.x*v.x + v.y*v.y + v.z*v.z + v.w*v.w;
                float x0 = v.x * rms_w[4*q+0], x1 = v.y * rms_w[4*q+1];
                float x2 = v.z * rms_w[4*q+2], x3 = v.w * rms_w[4*q+3];
#pragma unroll
                for (int c2 = 0; c2 < 16; ++c2) {
                    za[c2] = fmaf(x0, Wz[(4*q+0)*16 + c2], za[c2]);
                    za[c2] = fmaf(x1, Wz[(4*q+1)*16 + c2], za[c2]);
                    za[c2] = fmaf(x2, Wz[(4*q+2)*16 + c2], za[c2]);
                    za[c2] = fmaf(x3, Wz[(4*q+3)*16 + c2], za[c2]);
                }
            }
            float scale = rsqrtf(ss * (1.0f / 128.0f) + 1e-6f);
#pragma unroll
            for (int c2 = 0; c2 < 16; ++c2) p[c2] += za[c2] * scale;
        }
    }
    // motif position pairs
    if (load_mask(is_motif_coord, l, fmt) && load_mask(is_motif_coord, j, fmt)) {
        float d0 = motif_pos[l*3+0] - motif_pos[j*3+0];
        float d1 = motif_pos[l*3+1] - motif_pos[j*3+1];
        float d2 = motif_pos[l*3+2] - motif_pos[j*3+2];
        float invd = 1.0f / (1.0f + d0*d0 + d1*d1 + d2*d2);
#pragma unroll
        for (int c2 = 0; c2 < 16; ++c2)
            p[c2] += d0*Wdm[c2] + d1*Wdm[16+c2] + d2*Wdm[32+c2] + invd*Winvm[c2] + Wmaskm[c2];
    }
    // ref position pairs
    if (load_mask(is_motif_seq, l, fmt) && (ref_uid[j] == ref_uid[l]) && load_mask(is_motif_seq, j, fmt)) {
        float d0 = ref_pos[l*3+0] - ref_pos[j*3+0];
        float d1 = ref_pos[l*3+1] - ref_pos[j*3+1];
        float d2 = ref_pos[l*3+2] - ref_pos[j*3+2];
        float invd = 1.0f / (1.0f + d0*d0 + d1*d1 + d2*d2);
#pragma unroll
        for (int c2 = 0; c2 < 16; ++c2)
            p[c2] += d0*Wdr[c2] + d1*Wdr[16+c2] + d2*Wdr[32+c2] + invd*Winvr[c2] + Wmaskr[c2];
    }
    // residual MLP: 3x (relu -> 16x16 linear), weights are wave-uniform scalar loads
    float a[16], b[16];
#pragma unroll
    for (int c2 = 0; c2 < 16; ++c2) a[c2] = 0.f;
#pragma unroll
    for (int t = 0; t < 16; ++t) {
        float pt = fmaxf(p[t], 0.f);
#pragma unroll
        for (int c2 = 0; c2 < 16; ++c2) a[c2] = fmaf(pt, W1[t*16 + c2], a[c2]);
    }
#pragma unroll
    for (int c2 = 0; c2 < 16; ++c2) b[c2] = 0.f;
#pragma unroll
    for (int t = 0; t < 16; ++t) {
        float at = fmaxf(a[t], 0.f);
#pragma unroll
        for (int c2 = 0; c2 < 16; ++c2) b[c2] = fmaf(at, W2[t*16 + c2], b[c2]);
    }
#pragma unroll
    for (int c2 = 0; c2 < 16; ++c2) a[c2] = 0.f;
#pragma unroll
    for (int t = 0; t < 16; ++t) {
        float bt = fmaxf(b[t], 0.f);
#pragma unroll
        for (int c2 = 0; c2 < 16; ++c2) a[c2] = fmaf(bt, W3[t*16 + c2], a[c2]);
    }
    float4* o4 = (float4*)(out + (size_t)row * 16);
#pragma unroll
    for (int q = 0; q < 4; ++q) {
        float4 o;
        o.x = p[4*q+0] + a[4*q+0]; o.y = p[4*q+1] + a[4*q+1];
        o.z = p[4*q+2] + a[4*q+2]; o.w = p[4*q+3] + a[4*q+3];
        o4[q] = o;
    }
}

extern "C" void kernel_launch(void* const* d_in, const int* in_sizes, int n_in,
                              void* d_out, int out_size, void* d_ws, size_t ws_size,
                              hipStream_t stream) {
    const float* motif_pos       = (const float*)d_in[0];
    const unsigned char* is_mc   = (const unsigned char*)d_in[1];
    const float* ref_pos         = (const float*)d_in[2];
    const int*   ref_uid         = (const int*)d_in[3];
    const unsigned char* is_ms   = (const unsigned char*)d_in[4];
    const int*   indices         = (const int*)d_in[5];
    const float* C_L             = (const float*)d_in[6];
    const float* Z               = (const float*)d_in[7];
    const int*   tok_idx         = (const int*)d_in[8];
    const float* Wdm             = (const float*)d_in[9];
    const float* Winvm           = (const float*)d_in[10];
    const float* Wmaskm          = (const float*)d_in[11];
    const float* Wdr             = (const float*)d_in[12];
    const float* Winvr           = (const float*)d_in[13];
    const float* Wmaskr          = (const float*)d_in[14];
    const float* Wsl             = (const float*)d_in[15];
    const float* Wsm             = (const float*)d_in[16];
    const float* rms_w           = (const float*)d_in[17];
    const float* Wz              = (const float*)d_in[18];
    const float* W1              = (const float*)d_in[19];
    const float* W2              = (const float*)d_in[20];
    const float* W3              = (const float*)d_in[21];

    // workspace layout (floats): S_l | S_m | flag | (pad) | Zp
    float* S_l = (float*)d_ws;
    float* S_m = S_l + (size_t)BDIM * LDIM * CAD;                  // 393216
    int*   flag = (int*)(S_m + (size_t)BDIM * LDIM * CAD);
    float* Zp  = (float*)d_ws + 786448;                            // 16B-aligned
    const size_t full_bytes = ((size_t)786448 + (size_t)IDIM * IDIM * CAD) * 4;
    const bool full = ws_size >= full_bytes;

    k_single<<<dim3(768), dim3(256), 0, stream>>>(C_L, Wsl, Wsm, is_ms, S_l, S_m, flag);
    if (full) {
        k_zproc<<<dim3(2304), dim3(256), 0, stream>>>(Z, rms_w, Wz, Zp);
        k_pair<1><<<dim3((BDIM * LDIM * KDIM) / 256), dim3(256), 0, stream>>>(
            motif_pos, is_mc, ref_pos, ref_uid, is_ms, indices, tok_idx,
            Wdm, Winvm, Wmaskm, Wdr, Winvr, Wmaskr,
            S_l, S_m, Zp, Z, rms_w, Wz, W1, W2, W3, flag, (float*)d_out);
    } else {
        k_pair<0><<<dim3((BDIM * LDIM * KDIM) / 256), dim3(256), 0, stream>>>(
            motif_pos, is_mc, ref_pos, ref_uid, is_ms, indices, tok_idx,
            Wdm, Winvm, Wmaskm, Wdr, Winvr, Wmaskr,
            S_l, S_m, Zp, Z, rms_w, Wz, W1, W2, W3, flag, (float*)d_out);
    }
}